// Round 1
// baseline (46.216 us; speedup 1.0000x reference)
//
#include <hip/hip_runtime.h>
#include <math.h>

#define D   512
#define TPI 128   // threads per batch item (each owns 4 consecutive shifts)
#define IPB 2     // items per block

__global__ __launch_bounds__(256, 2) void hole_score_kernel(
    const float* __restrict__ ew, const float* __restrict__ eb,
    const float* __restrict__ rw, const float* __restrict__ rb,
    const int* __restrict__ xs, const int* __restrict__ ys,
    const int* __restrict__ rs, float* __restrict__ out)
{
    __shared__ float sa [IPB][D];        // a = ew[x]+eb[x]
    __shared__ float sbb[IPB][2 * D];    // b doubled for circular wrap
    __shared__ float sred[IPB][2];

    const int il   = threadIdx.x / TPI;      // item within block
    const int t    = threadIdx.x % TPI;      // 0..127
    const int item = blockIdx.x * IPB + il;

    const int xi = xs[item];
    const int yi = ys[item];
    const int ri = rs[item];

    // ---- stage a = entity_w[x] + entity_b[x] (one float4 per thread) ----
    {
        const float4 w4 = ((const float4*)(ew + (size_t)xi * D))[t];
        const float4 b4 = ((const float4*)(eb + (size_t)xi * D))[t];
        float4 v;
        v.x = w4.x + b4.x; v.y = w4.y + b4.y;
        v.z = w4.z + b4.z; v.w = w4.w + b4.w;
        ((float4*)sa[il])[t] = v;
    }
    // ---- stage b doubled: bb[k] = b[k mod 512] ----
    {
        const float4 w4 = ((const float4*)(ew + (size_t)yi * D))[t];
        const float4 b4 = ((const float4*)(eb + (size_t)yi * D))[t];
        float4 v;
        v.x = w4.x + b4.x; v.y = w4.y + b4.y;
        v.z = w4.z + b4.z; v.w = w4.w + b4.w;
        ((float4*)sbb[il])[t]       = v;
        ((float4*)sbb[il])[t + TPI] = v;
    }
    __syncthreads();

    // ---- sliding-window correlation: thread owns shifts i0..i0+3 ----
    // dot_s = sum_j a[j] * b[(j - (i0+s)) mod 512] = sum_j a[j] * bb[512 + j - i0 - s]
    const int i0 = 4 * t;
    const float* bbp = &sbb[il][D - i0];   // bbp[j + c - 4] window access
    const float* ap  = sa[il];

    float acc0 = 0.f, acc1 = 0.f, acc2 = 0.f, acc3 = 0.f;
    float4 prev = *(const float4*)(bbp - 4);

    #pragma unroll 4
    for (int j = 0; j < D; j += 4) {
        const float4 nb = *(const float4*)(bbp + j);  // contiguous, conflict-free
        const float4 av = *(const float4*)(ap + j);   // wave-uniform broadcast
        // window w[0..7] = {prev.x..prev.w, nb.x..nb.w}; acc_s += av[d]*w[d-s+4]
        acc0 += av.x * nb.x   + av.y * nb.y   + av.z * nb.z   + av.w * nb.w;
        acc1 += av.x * prev.w + av.y * nb.x   + av.z * nb.y   + av.w * nb.z;
        acc2 += av.x * prev.z + av.y * prev.w + av.z * nb.x   + av.w * nb.y;
        acc3 += av.x * prev.y + av.y * prev.z + av.z * prev.w + av.w * nb.x;
        prev = nb;
    }

    // ---- epilogue: rel[i0+s] straight from global (coalesced float4) ----
    const float4 rw4 = ((const float4*)(rw + (size_t)ri * D))[t];
    const float4 rb4 = ((const float4*)(rb + (size_t)ri * D))[t];
    float part = (rw4.x + rb4.x) * acc0 + (rw4.y + rb4.y) * acc1
               + (rw4.z + rb4.z) * acc2 + (rw4.w + rb4.w) * acc3;

    // wave64 reduce
    #pragma unroll
    for (int off = 32; off >= 1; off >>= 1)
        part += __shfl_down(part, off, 64);

    const int lane = threadIdx.x & 63;
    const int wii  = (t >= 64) ? 1 : 0;
    if (lane == 0) sred[il][wii] = part;
    __syncthreads();

    if (t == 0) {
        float s = (sred[il][0] + sred[il][1]) * (1.0f / (float)D);
        out[item] = 1.0f / (1.0f + expf(-s));
    }
}

extern "C" void kernel_launch(void* const* d_in, const int* in_sizes, int n_in,
                              void* d_out, int out_size, void* d_ws, size_t ws_size,
                              hipStream_t stream)
{
    const float* ew = (const float*)d_in[0];
    const float* eb = (const float*)d_in[1];
    const float* rw = (const float*)d_in[2];
    const float* rb = (const float*)d_in[3];
    const int*   xs = (const int*)d_in[4];
    const int*   ys = (const int*)d_in[5];
    const int*   rs = (const int*)d_in[6];
    float* out = (float*)d_out;

    const int batch = in_sizes[4];           // 4096
    dim3 grid(batch / IPB), block(IPB * TPI);
    hole_score_kernel<<<grid, block, 0, stream>>>(ew, eb, rw, rb, xs, ys, rs, out);
}

// Round 2
// 37.645 us; speedup vs baseline: 1.2277x; 1.2277x over previous
//
#include <hip/hip_runtime.h>
#include <math.h>

#define D    512
#define IPB  4                      // items per block, 1 wave (64 lanes) each
#define SWZ(f) ((f) ^ (((f) >> 3) & 7))   // bank-group swizzle on float4 slots

__global__ __launch_bounds__(IPB * 64, 4) void hole_score_kernel(
    const float* __restrict__ ew, const float* __restrict__ eb,
    const float* __restrict__ rw, const float* __restrict__ rb,
    const int* __restrict__ xs, const int* __restrict__ ys,
    const int* __restrict__ rs, float* __restrict__ out)
{
    __shared__ float4 sa [IPB][D / 4];        // a = ew[x]+eb[x], linear
    __shared__ float4 sbb[IPB][2 * D / 4];    // b doubled for wrap, XOR-swizzled

    const int il   = threadIdx.x >> 6;        // item within block
    const int l    = threadIdx.x & 63;        // lane
    const int g    = l & 31;                  // owns shifts [16g, 16g+16)
    const int jh   = l >> 5;                  // j-half: [256*jh, 256*jh+256)
    const int item = blockIdx.x * IPB + il;

    const int xi = xs[item], yi = ys[item], ri = rs[item];

    // ---- stage a = entity_w[x] + entity_b[x] (2 float4 per lane, coalesced) ----
    {
        const float4* w4 = (const float4*)(ew + (size_t)xi * D);
        const float4* b4 = (const float4*)(eb + (size_t)xi * D);
        float4 u0 = w4[l],      v0 = b4[l];
        float4 u1 = w4[l + 64], v1 = b4[l + 64];
        sa[il][l]      = make_float4(u0.x+v0.x, u0.y+v0.y, u0.z+v0.z, u0.w+v0.w);
        sa[il][l + 64] = make_float4(u1.x+v1.x, u1.y+v1.y, u1.z+v1.z, u1.w+v1.w);
    }
    // ---- stage b doubled + swizzled: logical slot f holds b floats [4f mod 512 ..) ----
    {
        const float4* w4 = (const float4*)(ew + (size_t)yi * D);
        const float4* b4 = (const float4*)(eb + (size_t)yi * D);
        float4 u0 = w4[l],      v0 = b4[l];
        float4 u1 = w4[l + 64], v1 = b4[l + 64];
        float4 r0 = make_float4(u0.x+v0.x, u0.y+v0.y, u0.z+v0.z, u0.w+v0.w);
        float4 r1 = make_float4(u1.x+v1.x, u1.y+v1.y, u1.z+v1.z, u1.w+v1.w);
        sbb[il][SWZ(l)]            = r0;   // sigma(f+128) == sigma(f)+128
        sbb[il][SWZ(l + 64)]       = r1;
        sbb[il][SWZ(l) + 128]      = r0;
        sbb[il][SWZ(l + 64) + 128] = r1;
    }
    __syncthreads();

    const float4* bbp = sbb[il];
    const float4* ap  = sa[il];

    float acc[16];
    #pragma unroll
    for (int u = 0; u < 16; ++u) acc[u] = 0.f;

    // sliding 32-float window: wOLD = bb floats [512+J-16g-16 ..), wNEW = [512+J-16g ..)
    float wA[16], wB[16];

    int fb = 128 + (jh << 6) - (g << 2);  // float4 slot of window start at J0
    int jc = jh << 6;                     // a float4-slot base

    // prologue: fill wA with floats [J0-16, J0)
    #pragma unroll
    for (int q = 0; q < 4; ++q) {
        const float4 t = bbp[SWZ(fb - 4 + q)];
        wA[4*q+0]=t.x; wA[4*q+1]=t.y; wA[4*q+2]=t.z; wA[4*q+3]=t.w;
    }

    // one macro-step: 16 js, 16 shifts -> 256 FMAs, 8 ds_read_b128
#define STEP(WOLD, WNEW)                                                \
    do {                                                                \
        float av[16];                                                   \
        _Pragma("unroll")                                               \
        for (int q = 0; q < 4; ++q) {                                   \
            const float4 tb = bbp[SWZ(fb + q)];                         \
            WNEW[4*q+0]=tb.x; WNEW[4*q+1]=tb.y;                         \
            WNEW[4*q+2]=tb.z; WNEW[4*q+3]=tb.w;                         \
            const float4 ta = ap[jc + q];                               \
            av[4*q+0]=ta.x; av[4*q+1]=ta.y;                             \
            av[4*q+2]=ta.z; av[4*q+3]=ta.w;                             \
        }                                                               \
        _Pragma("unroll")                                               \
        for (int c = 0; c < 16; ++c) {                                  \
            _Pragma("unroll")                                           \
            for (int u = 0; u < 16; ++u) {                              \
                const int wi = 16 + c - u; /* in [1,31] */              \
                acc[u] += av[c] * ((wi < 16) ? WOLD[wi] : WNEW[wi-16]); \
            }                                                           \
        }                                                               \
        fb += 4; jc += 4;                                               \
    } while (0)

    #pragma unroll 1
    for (int kk = 0; kk < 8; ++kk) {   // 16 macro-steps, buffer-swap period 2
        STEP(wA, wB);
        STEP(wB, wA);
    }
#undef STEP

    // ---- epilogue: rel dot, straight from global (L1/L2-cached) ----
    const float4* rwp = (const float4*)(rw + (size_t)ri * D);
    const float4* rbp = (const float4*)(rb + (size_t)ri * D);
    float part = 0.f;
    #pragma unroll
    for (int q = 0; q < 4; ++q) {
        const float4 rA = rwp[(g << 2) + q];
        const float4 rB = rbp[(g << 2) + q];
        part += (rA.x + rB.x) * acc[4*q+0]
              + (rA.y + rB.y) * acc[4*q+1]
              + (rA.z + rB.z) * acc[4*q+2]
              + (rA.w + rB.w) * acc[4*q+3];
    }

    #pragma unroll
    for (int off = 32; off >= 1; off >>= 1)
        part += __shfl_down(part, off, 64);

    if (l == 0)
        out[item] = 1.0f / (1.0f + expf(-part * (1.0f / (float)D)));
}

extern "C" void kernel_launch(void* const* d_in, const int* in_sizes, int n_in,
                              void* d_out, int out_size, void* d_ws, size_t ws_size,
                              hipStream_t stream)
{
    const float* ew = (const float*)d_in[0];
    const float* eb = (const float*)d_in[1];
    const float* rw = (const float*)d_in[2];
    const float* rb = (const float*)d_in[3];
    const int*   xs = (const int*)d_in[4];
    const int*   ys = (const int*)d_in[5];
    const int*   rs = (const int*)d_in[6];
    float* out = (float*)d_out;

    const int batch = in_sizes[4];   // 4096
    dim3 grid(batch / IPB), block(IPB * 64);
    hole_score_kernel<<<grid, block, 0, stream>>>(ew, eb, rw, rb, xs, ys, rs, out);
}